// Round 14
// baseline (103.341 us; speedup 1.0000x reference)
//
#include <hip/hip_runtime.h>
#include <hip/hip_bf16.h>
#include <stdint.h>

typedef unsigned short u16;
typedef unsigned int u32;
typedef __bf16 bf16x8 __attribute__((ext_vector_type(8)));
typedef float f32x4 __attribute__((ext_vector_type(4)));

// B=8, C=512, T=1024, heads=8, ch=64, groups=32 (16 ch/group)

static __device__ __forceinline__ u16 f2bf(float f) {
  union { __hip_bfloat16 h; u16 u; } c;
  c.h = __float2bfloat16(f);
  return c.u;
}

// truncating f32->bf16 (1 op); valid for P>0, bias cancels in softmax normalization
static __device__ __forceinline__ u16 f2bf_t(float f) {
  union { float f; u32 u; } c;
  c.f = f;
  return (u16)(c.u >> 16);
}

static __device__ __forceinline__ void gload_lds16(const void* g, void* l) {
  __builtin_amdgcn_global_load_lds(
      (__attribute__((address_space(1))) u32*)(uintptr_t)g,
      (__attribute__((address_space(3))) u32*)l, 16, 0, 0);
}

// ---------------- fused: weight convert (blocks 256..1279) + GN stats (blocks 0..255) ----------------
__global__ __launch_bounds__(256) void prep(const float* __restrict__ wq,
                                            const float* __restrict__ wp,
                                            const float* __restrict__ x,
                                            u16* __restrict__ wqb,
                                            u16* __restrict__ wpb,
                                            float* __restrict__ st) {
  int blk = blockIdx.x;
  if (blk >= 256) {
    int idx = ((blk - 256) * 256 + threadIdx.x) * 4;
    const float* s;
    u16* d;
    if (idx < 786432) { s = wq + idx; d = wqb + idx; }
    else { int k = idx - 786432; s = wp + k; d = wpb + k; }
    float4 v = *(const float4*)s;
    uint2 o;
    o.x = (u32)f2bf(v.x) | ((u32)f2bf(v.y) << 16);
    o.y = (u32)f2bf(v.z) | ((u32)f2bf(v.w) << 16);
    *(uint2*)d = o;
    return;
  }
  int bg = blk;  // 0..255 ; group block is contiguous 16*1024 floats
  const float* p = x + (size_t)bg * 16384;
  float s1 = 0.f, s2 = 0.f;
  for (int i = threadIdx.x * 4; i < 16384; i += 1024) {
    float4 v = *(const float4*)(p + i);
    s1 += v.x + v.y + v.z + v.w;
    s2 += v.x * v.x + v.y * v.y + v.z * v.z + v.w * v.w;
  }
#pragma unroll
  for (int off = 1; off < 64; off <<= 1) {
    s1 += __shfl_xor(s1, off);
    s2 += __shfl_xor(s2, off);
  }
  __shared__ float r1[4], r2[4];
  int w = threadIdx.x >> 6, l = threadIdx.x & 63;
  if (l == 0) { r1[w] = s1; r2[w] = s2; }
  __syncthreads();
  if (threadIdx.x == 0) {
    float t1 = r1[0] + r1[1] + r1[2] + r1[3];
    float t2 = r2[0] + r2[1] + r2[2] + r2[3];
    float mean = t1 * (1.f / 16384.f);
    float var = t2 * (1.f / 16384.f) - mean * mean;
    st[bg * 2] = mean;
    st[bg * 2 + 1] = rsqrtf(var + 1e-5f);
  }
}

// ---------------- normalize + transpose: xnt[b][t][c] bf16; float4 x loads ----------------
__global__ __launch_bounds__(256) void gn_apply(const float* __restrict__ x,
                                                const float* __restrict__ st,
                                                const float* __restrict__ ns,
                                                const float* __restrict__ nbi,
                                                u16* __restrict__ xnt) {
  __shared__ u16 tile[32 * 520];  // [t_local][c], row padded to 520 (1040B, 16B-aligned)
  int b = blockIdx.x >> 5;
  int t0 = (blockIdx.x & 31) << 5;
  int tid = threadIdx.x;
  int tg = (tid & 7) * 4;   // 4 consecutive t per thread
  int c0 = tid >> 3;        // 32 c per pass
#pragma unroll 4
  for (int cc = 0; cc < 16; ++cc) {
    int c = cc * 32 + c0;
    float mean = st[(b * 32 + (c >> 4)) * 2];
    float rstd = st[(b * 32 + (c >> 4)) * 2 + 1];
    float sc = ns[c], bi = nbi[c];
    float4 v = *(const float4*)(x + (size_t)b * 524288 + (size_t)c * 1024 + t0 + tg);
    tile[(tg + 0) * 520 + c] = f2bf((v.x - mean) * rstd * sc + bi);
    tile[(tg + 1) * 520 + c] = f2bf((v.y - mean) * rstd * sc + bi);
    tile[(tg + 2) * 520 + c] = f2bf((v.z - mean) * rstd * sc + bi);
    tile[(tg + 3) * 520 + c] = f2bf((v.w - mean) * rstd * sc + bi);
  }
  __syncthreads();
#pragma unroll
  for (int i = 0; i < 8; ++i) {
    int chunk = i * 256 + tid;
    int tl2 = chunk >> 6;
    int c0b = (chunk & 63) * 8;
    uint4 d = *(const uint4*)(tile + tl2 * 520 + c0b);
    *(uint4*)(xnt + (size_t)b * 524288 + (size_t)(t0 + tl2) * 512 + c0b) = d;
  }
}

// ---------------- shared GEMM core: 128x128 tile, BK=64, K=512, single-buffer ----------------
// A: [M][512] bf16 row-major. B^T: [N][512] bf16 row-major. XOR-swizzled LDS.
static __device__ __forceinline__ void gemm_core(const u16* Abase, const u16* Bbase,
                                                 f32x4 acc[4][4], u16* As, u16* Bs,
                                                 int w, int l, int wm, int wn) {
  const int r8 = l >> 3, ch = l & 7;
  const int fr = l & 15, fq = l >> 4;
#pragma unroll 1
  for (int kt = 0; kt < 8; ++kt) {
    __syncthreads();
#pragma unroll
    for (int i = 0; i < 4; ++i) {
      int gi = (w << 2) + i;
      int row = (gi << 3) + r8;
      int xoff = ((ch ^ (row & 7)) << 4);
      gload_lds16((const char*)Abase + (size_t)row * 1024 + (kt << 7) + xoff,
                  (char*)As + (gi << 10));
      gload_lds16((const char*)Bbase + (size_t)row * 1024 + (kt << 7) + xoff,
                  (char*)Bs + (gi << 10));
    }
    __syncthreads();
#pragma unroll
    for (int kf = 0; kf < 2; ++kf) {
      bf16x8 af[4], bfv[4];
#pragma unroll
      for (int i = 0; i < 4; ++i) {
        int rowA = wm * 64 + i * 16 + fr;
        af[i] = *(const bf16x8*)(As + rowA * 64 + ((((kf << 2) + fq) ^ (rowA & 7)) << 3));
        int rowB = wn * 64 + i * 16 + fr;
        bfv[i] = *(const bf16x8*)(Bs + rowB * 64 + ((((kf << 2) + fq) ^ (rowB & 7)) << 3));
      }
#pragma unroll
      for (int i = 0; i < 4; ++i)
#pragma unroll
        for (int j = 0; j < 4; ++j)
          acc[i][j] = __builtin_amdgcn_mfma_f32_16x16x32_bf16(af[i], bfv[j], acc[i][j], 0, 0, 0);
    }
  }
}

// ---------------- QKV GEMM with LDS-transposed coalesced epilogue ----------------
__global__ __launch_bounds__(256) void gemm_qkv(const u16* __restrict__ Wq,
                                                const u16* __restrict__ Xnt,
                                                const float* __restrict__ bq,
                                                u16* __restrict__ qT,
                                                u16* __restrict__ kT,
                                                u16* __restrict__ vv) {
  __shared__ u16 SMEM[18432];  // gemm As=SMEM, Bs=SMEM+8192; epilogue SUB[wm]=SMEM+wm*9216
  int bid0 = blockIdx.x;
  int bid = (bid0 & 7) * 96 + (bid0 >> 3);  // bijective: 768 = 8*96
  int mb = bid % 12, nb = (bid / 12) % 8, b = bid / 96;
  int tid = threadIdx.x, w = tid >> 6, l = tid & 63;
  int wm = tid >> 7, wn = (tid >> 6) & 1;
  int fr = l & 15, fq = l >> 4;
  f32x4 acc[4][4];
#pragma unroll
  for (int i = 0; i < 4; ++i)
#pragma unroll
    for (int j = 0; j < 4; ++j) acc[i][j] = (f32x4){0.f, 0.f, 0.f, 0.f};

  gemm_core(Wq + (size_t)mb * 65536, Xnt + (size_t)b * 524288 + (size_t)nb * 65536,
            acc, SMEM, SMEM + 8192, w, l, wm, wn);

  __syncthreads();  // all gemm LDS reads done before epilogue overwrite

  int seg2 = mb * 2 + wm;       // 0..23: which 64-row o-segment
  int h = seg2 / 3, typ = seg2 % 3;  // 0=q 1=k 2=v
  size_t hb = (size_t)(b * 8 + h) * 65536;
  u16* SUB = SMEM + wm * 9216;

  if (typ < 2) {
    // q/k: SUB layout [t 128][72 pad], rows 144B (16B-aligned)
    float qksc = (typ == 0) ? 0.51011687f : 0.35355339f;  // q: 64^-.25*log2e ; k: 64^-.25
#pragma unroll
    for (int i = 0; i < 4; ++i) {
      int oi = i * 16 + fq * 4;
      float4 bb = *(const float4*)(bq + mb * 128 + wm * 64 + oi);
#pragma unroll
      for (int j = 0; j < 4; ++j) {
        int tl = wn * 64 + j * 16 + fr;
        f32x4 v = acc[i][j];
        uint2 pk;
        pk.x = (u32)f2bf((v[0] + bb.x) * qksc) | ((u32)f2bf((v[1] + bb.y) * qksc) << 16);
        pk.y = (u32)f2bf((v[2] + bb.z) * qksc) | ((u32)f2bf((v[3] + bb.w) * qksc) << 16);
        *(uint2*)(SUB + tl * 72 + oi) = pk;
      }
    }
  } else {
    // v: SUB layout [o 64][136 pad], rows 272B (16B-aligned)
#pragma unroll
    for (int i = 0; i < 4; ++i) {
      int oi = i * 16 + fq * 4;
      float4 bb = *(const float4*)(bq + mb * 128 + wm * 64 + oi);
      float bbv[4] = {bb.x, bb.y, bb.z, bb.w};
#pragma unroll
      for (int j = 0; j < 4; ++j) {
        int tl = wn * 64 + j * 16 + fr;
        f32x4 v = acc[i][j];
#pragma unroll
        for (int r = 0; r < 4; ++r)
          SUB[(oi + r) * 136 + tl] = f2bf(v[r] + bbv[r]);
      }
    }
  }
  __syncthreads();

  // coalesced store: each 128-thread half stores its own sub-tile
  int lt = tid & 127;
  if (typ < 2) {
    u16* dstb = (typ == 0 ? qT : kT) + hb;
#pragma unroll
    for (int it = 0; it < 8; ++it) {
      int slot = it * 128 + lt;
      int t = slot >> 3, chk = slot & 7;
      uint4 val = *(const uint4*)(SUB + t * 72 + chk * 8);
      *(uint4*)(dstb + (size_t)(nb * 128 + t) * 64 + chk * 8) = val;
    }
  } else {
#pragma unroll
    for (int it = 0; it < 8; ++it) {
      int slot = it * 128 + lt;
      int c = slot >> 4, chk = slot & 15;
      uint4 val = *(const uint4*)(SUB + c * 136 + chk * 8);
      *(uint4*)(vv + hb + (size_t)c * 1024 + nb * 128 + chk * 8) = val;
    }
  }
}

// ---------------- flash attention: T14 async-STAGE (issue-early / write-late) ----------------
// KVBLK=128, 8-wave blocks. Reg-staged K/V: global loads issued BEFORE compute
// (latency hides under QK+softmax+PV), ds_write after the post-compute barrier.
__global__ __launch_bounds__(512) void attn(const u16* __restrict__ qT,
                                            const u16* __restrict__ kT,
                                            const u16* __restrict__ vv,
                                            u16* __restrict__ aT) {
  __shared__ u16 Ks[128 * 64];      // [s 128][c 64] swizzled, 16KB
  __shared__ u16 Vs[64 * 128];      // [c 64][s 128] swizzled (XOR within 128B half), 16KB
  __shared__ u16 Ps[8 * 16 * 72];   // per-wave P tile [16 t][64 s], row pad->72 (144B)
  int bid = blockIdx.x;
  // XCD swizzle: XCD x owns heads 8x..8x+7 -> 2MB K/V resident per XCD L2
  int bh = (bid & 7) * 8 + (bid >> 6);
  int tq = (bid >> 3) & 7;
  int tid = threadIdx.x, w = tid >> 6, l = tid & 63;
  int fr = l & 15, fq = l >> 4;
  int r8 = l >> 3, ch = l & 7;
  size_t hb = (size_t)bh * 65536;

  bf16x8 aq[2];  // Q frags, loop-invariant (q pre-scaled by 64^-0.25*log2e)
  {
    const u16* qp = qT + hb + (size_t)(tq * 128 + w * 16 + fr) * 64 + fq * 8;
    aq[0] = *(const bf16x8*)(qp);
    aq[1] = *(const bf16x8*)(qp + 32);
  }

  // per-lane staging addresses (source swizzled, LDS dest linear = base+lane*16)
  const char* ksrc[2];
  const char* vsrc[2];
  char* kdst[2];
  char* vdst[2];
#pragma unroll
  for (int j = 0; j < 2; ++j) {
    int gi = w * 2 + j;
    int row = gi * 8 + r8;
    int xoff = ((ch ^ (row & 7)) << 4);
    ksrc[j] = (const char*)(kT + hb) + (size_t)row * 128 + xoff;   // + st*128*128
    kdst[j] = (char*)Ks + (gi << 10) + l * 16;
    int c = gi * 4 + (l >> 4);
    int half = (l >> 3) & 1;
    int ch8 = l & 7;
    int sxoff = half * 128 + ((ch8 ^ (c & 7)) << 4);
    vsrc[j] = (const char*)(vv + hb) + (size_t)c * 2048 + sxoff;   // + st*256
    vdst[j] = (char*)Vs + (gi << 10) + l * 16;
  }

  union { u32 u[4]; bf16x8 v; } onesu;
#pragma unroll
  for (int i = 0; i < 4; ++i) onesu.u[i] = 0x3F803F80u;
  const bf16x8 vone = onesu.v;  // all-ones B frag: every output col = row-sum

  f32x4 acc_o[4];
  f32x4 acc_s = (f32x4){0.f, 0.f, 0.f, 0.f};
#pragma unroll
  for (int nb = 0; nb < 4; ++nb) acc_o[nb] = (f32x4){0.f, 0.f, 0.f, 0.f};

  u16* pw = Ps + w * (16 * 72);

  // prologue: stage tile 0 directly
  {
    uint4 kr0 = *(const uint4*)(ksrc[0]);
    uint4 kr1 = *(const uint4*)(ksrc[1]);
    uint4 vr0 = *(const uint4*)(vsrc[0]);
    uint4 vr1 = *(const uint4*)(vsrc[1]);
    *(uint4*)(kdst[0]) = kr0;
    *(uint4*)(kdst[1]) = kr1;
    *(uint4*)(vdst[0]) = vr0;
    *(uint4*)(vdst[1]) = vr1;
  }
  __syncthreads();

#pragma unroll 1
  for (int st = 0; st < 8; ++st) {
    // T14 issue-early: next tile's global loads fly during compute
    uint4 kreg[2], vreg[2];
    if (st < 7) {
#pragma unroll
      for (int j = 0; j < 2; ++j) {
        kreg[j] = *(const uint4*)(ksrc[j] + (size_t)(st + 1) * 16384);
        vreg[j] = *(const uint4*)(vsrc[j] + (size_t)(st + 1) * 256);
      }
    }

#pragma unroll
    for (int sh = 0; sh < 2; ++sh) {
      // S' = log2e*(q.k)/8 : D[t][s], 16x64 per wave per half
      f32x4 sa[4];
#pragma unroll
      for (int nb = 0; nb < 4; ++nb) sa[nb] = (f32x4){0.f, 0.f, 0.f, 0.f};
      __builtin_amdgcn_s_setprio(1);
#pragma unroll
      for (int nb = 0; nb < 4; ++nb) {
        int krow = sh * 64 + nb * 16 + fr;
#pragma unroll
        for (int kf = 0; kf < 2; ++kf) {
          bf16x8 bk = *(const bf16x8*)(Ks + krow * 64 + ((((kf << 2) + fq) ^ (krow & 7)) << 3));
          sa[nb] = __builtin_amdgcn_mfma_f32_16x16x32_bf16(aq[kf], bk, sa[nb], 0, 0, 0);
        }
      }
      __builtin_amdgcn_s_setprio(0);

      // P = 2^S' (no max subtraction); truncating bf16 cvt (bias cancels via acc_s)
#pragma unroll
      for (int nb = 0; nb < 4; ++nb)
#pragma unroll
        for (int r = 0; r < 4; ++r)
          pw[(fq * 4 + r) * 72 + nb * 16 + fr] = f2bf_t(exp2f(sa[nb][r]));

      bf16x8 ap[2];  // wave-private LDS round-trip
#pragma unroll
      for (int kf = 0; kf < 2; ++kf)
        ap[kf] = *(const bf16x8*)(pw + fr * 72 + kf * 32 + fq * 8);

      __builtin_amdgcn_s_setprio(1);
#pragma unroll
      for (int nb = 0; nb < 4; ++nb) {
        int vrow = nb * 16 + fr;
#pragma unroll
        for (int kf = 0; kf < 2; ++kf) {
          bf16x8 bv = *(const bf16x8*)(Vs + vrow * 128 + sh * 64 +
                                       ((((kf << 2) + fq) ^ (vrow & 7)) << 3));
          acc_o[nb] = __builtin_amdgcn_mfma_f32_16x16x32_bf16(ap[kf], bv, acc_o[nb], 0, 0, 0);
        }
      }
#pragma unroll
      for (int kf = 0; kf < 2; ++kf)
        acc_s = __builtin_amdgcn_mfma_f32_16x16x32_bf16(ap[kf], vone, acc_s, 0, 0, 0);
      __builtin_amdgcn_s_setprio(0);
    }

    // T14 write-late: after all waves finish reading tile st, commit tile st+1
    if (st < 7) {
      __syncthreads();  // LDS reads of tile st complete
#pragma unroll
      for (int j = 0; j < 2; ++j) {
        *(uint4*)(kdst[j]) = kreg[j];  // vmcnt wait: loads issued a full phase ago
        *(uint4*)(vdst[j]) = vreg[j];
      }
      __syncthreads();  // writes visible
    }
  }

  int b = bh >> 3, h = bh & 7;
  f32x4 invl;  // acc_s rows align with acc_o rows -> no shuffle needed
#pragma unroll
  for (int r = 0; r < 4; ++r) invl[r] = 1.f / acc_s[r];
#pragma unroll
  for (int nb = 0; nb < 4; ++nb) {
    f32x4 ov = acc_o[nb] * invl;
#pragma unroll
    for (int r = 0; r < 4; ++r) {
      int t = tq * 128 + w * 16 + fq * 4 + r;
      aT[(size_t)b * 524288 + (size_t)t * 512 + h * 64 + nb * 16 + fr] = f2bf(ov[r]);
    }
  }
}

// ---------------- proj GEMM + residual ----------------
__global__ __launch_bounds__(256) void gemm_proj(const u16* __restrict__ Wp,
                                                 const u16* __restrict__ aT,
                                                 const float* __restrict__ bp,
                                                 const float* __restrict__ x,
                                                 float* __restrict__ out) {
  __shared__ u16 As[128 * 64];
  __shared__ u16 Bs[128 * 64];
  int bid0 = blockIdx.x;
  int bid = (bid0 & 7) * 32 + (bid0 >> 3);  // bijective: 256 = 8*32
  int mb = bid & 3, nb = (bid >> 2) & 7, b = bid >> 5;
  int tid = threadIdx.x, w = tid >> 6, l = tid & 63;
  int wm = w >> 1, wn = w & 1;
  f32x4 acc[4][4];
#pragma unroll
  for (int i = 0; i < 4; ++i)
#pragma unroll
    for (int j = 0; j < 4; ++j) acc[i][j] = (f32x4){0.f, 0.f, 0.f, 0.f};

  gemm_core(Wp + (size_t)mb * 65536, aT + (size_t)b * 524288 + (size_t)nb * 65536,
            acc, As, Bs, w, l, wm, wn);

  int fr = l & 15, fq = l >> 4;
#pragma unroll
  for (int i = 0; i < 4; ++i) {
    int o0 = mb * 128 + wm * 64 + i * 16 + fq * 4;
    float b0 = bp[o0], b1 = bp[o0 + 1], b2 = bp[o0 + 2], b3 = bp[o0 + 3];
#pragma unroll
    for (int j = 0; j < 4; ++j) {
      int t = nb * 128 + wn * 64 + j * 16 + fr;
      f32x4 v = acc[i][j];
      size_t base = (size_t)b * 524288 + (size_t)o0 * 1024 + t;
      out[base] = x[base] + v[0] + b0;
      out[base + 1024] = x[base + 1024] + v[1] + b1;
      out[base + 2048] = x[base + 2048] + v[2] + b2;
      out[base + 3072] = x[base + 3072] + v[3] + b3;
    }
  }
}

extern "C" void kernel_launch(void* const* d_in, const int* in_sizes, int n_in,
                              void* d_out, int out_size, void* d_ws, size_t ws_size,
                              hipStream_t stream) {
  const float* x = (const float*)d_in[0];
  const float* ns = (const float*)d_in[1];
  const float* nbi = (const float*)d_in[2];
  const float* wq = (const float*)d_in[3];
  const float* bq = (const float*)d_in[4];
  const float* wp = (const float*)d_in[5];
  const float* bp = (const float*)d_in[6];
  float* out = (float*)d_out;
  char* ws = (char*)d_ws;

  u16* wqb = (u16*)(ws);                          // 1,572,864 B
  u16* wpb = (u16*)(ws + 1572864);                //   524,288 B
  float* st = (float*)(ws + 2097152);             //     2,048 B
  u16* xnt = (u16*)(ws + 2101248);                // 8,388,608 B  [b][t][c] bf16
  u16* qT = (u16*)(ws + 2101248 + 8388608);       // 8,388,608 B  [bh][t][64] bf16 (pre-scaled)
  u16* kT = (u16*)(ws + 2101248 + 2 * 8388608);   // 8,388,608 B  [bh][s][64] bf16 (pre-scaled)
  u16* vv = (u16*)(ws + 2101248 + 3 * 8388608);   // 8,388,608 B  [bh][64][s] bf16
  u16* aT = xnt;  // reuse: xnt fully consumed by gemm_qkv before attn writes aT

  hipLaunchKernelGGL(prep, dim3(1280), dim3(256), 0, stream, wq, wp, x, wqb, wpb, st);
  hipLaunchKernelGGL(gn_apply, dim3(256), dim3(256), 0, stream, x, st, ns, nbi, xnt);
  hipLaunchKernelGGL(gemm_qkv, dim3(768), dim3(256), 0, stream, wqb, xnt, bq, qT, kT, vv);
  hipLaunchKernelGGL(attn, dim3(512), dim3(512), 0, stream, qT, kT, vv, aT);
  hipLaunchKernelGGL(gemm_proj, dim3(256), dim3(256), 0, stream, wpb, aT, bp, x, out);
}

// Round 15
// 87.623 us; speedup vs baseline: 1.1794x; 1.1794x over previous
//
#include <hip/hip_runtime.h>
#include <hip/hip_bf16.h>
#include <stdint.h>

typedef unsigned short u16;
typedef unsigned int u32;
typedef __bf16 bf16x8 __attribute__((ext_vector_type(8)));
typedef float f32x4 __attribute__((ext_vector_type(4)));

// B=8, C=512, T=1024, heads=8, ch=64, groups=32 (16 ch/group)

static __device__ __forceinline__ u16 f2bf(float f) {
  union { __hip_bfloat16 h; u16 u; } c;
  c.h = __float2bfloat16(f);
  return c.u;
}

// truncating f32->bf16 (1 op); valid for P>0, bias cancels in softmax normalization
static __device__ __forceinline__ u16 f2bf_t(float f) {
  union { float f; u32 u; } c;
  c.f = f;
  return (u16)(c.u >> 16);
}

static __device__ __forceinline__ void gload_lds16(const void* g, void* l) {
  __builtin_amdgcn_global_load_lds(
      (__attribute__((address_space(1))) u32*)(uintptr_t)g,
      (__attribute__((address_space(3))) u32*)l, 16, 0, 0);
}

// ---------------- fused: weight convert (blocks 256..1279) + GN stats (blocks 0..255) ----------------
__global__ __launch_bounds__(256) void prep(const float* __restrict__ wq,
                                            const float* __restrict__ wp,
                                            const float* __restrict__ x,
                                            u16* __restrict__ wqb,
                                            u16* __restrict__ wpb,
                                            float* __restrict__ st) {
  int blk = blockIdx.x;
  if (blk >= 256) {
    int idx = ((blk - 256) * 256 + threadIdx.x) * 4;
    const float* s;
    u16* d;
    if (idx < 786432) { s = wq + idx; d = wqb + idx; }
    else { int k = idx - 786432; s = wp + k; d = wpb + k; }
    float4 v = *(const float4*)s;
    uint2 o;
    o.x = (u32)f2bf(v.x) | ((u32)f2bf(v.y) << 16);
    o.y = (u32)f2bf(v.z) | ((u32)f2bf(v.w) << 16);
    *(uint2*)d = o;
    return;
  }
  int bg = blk;  // 0..255 ; group block is contiguous 16*1024 floats
  const float* p = x + (size_t)bg * 16384;
  float s1 = 0.f, s2 = 0.f;
  for (int i = threadIdx.x * 4; i < 16384; i += 1024) {
    float4 v = *(const float4*)(p + i);
    s1 += v.x + v.y + v.z + v.w;
    s2 += v.x * v.x + v.y * v.y + v.z * v.z + v.w * v.w;
  }
#pragma unroll
  for (int off = 1; off < 64; off <<= 1) {
    s1 += __shfl_xor(s1, off);
    s2 += __shfl_xor(s2, off);
  }
  __shared__ float r1[4], r2[4];
  int w = threadIdx.x >> 6, l = threadIdx.x & 63;
  if (l == 0) { r1[w] = s1; r2[w] = s2; }
  __syncthreads();
  if (threadIdx.x == 0) {
    float t1 = r1[0] + r1[1] + r1[2] + r1[3];
    float t2 = r2[0] + r2[1] + r2[2] + r2[3];
    float mean = t1 * (1.f / 16384.f);
    float var = t2 * (1.f / 16384.f) - mean * mean;
    st[bg * 2] = mean;
    st[bg * 2 + 1] = rsqrtf(var + 1e-5f);
  }
}

// ---------------- normalize + transpose: xnt[b][t][c] bf16; float4 x loads ----------------
__global__ __launch_bounds__(256) void gn_apply(const float* __restrict__ x,
                                                const float* __restrict__ st,
                                                const float* __restrict__ ns,
                                                const float* __restrict__ nbi,
                                                u16* __restrict__ xnt) {
  __shared__ u16 tile[32 * 520];  // [t_local][c], row padded to 520 (1040B, 16B-aligned)
  int b = blockIdx.x >> 5;
  int t0 = (blockIdx.x & 31) << 5;
  int tid = threadIdx.x;
  int tg = (tid & 7) * 4;   // 4 consecutive t per thread
  int c0 = tid >> 3;        // 32 c per pass
#pragma unroll 4
  for (int cc = 0; cc < 16; ++cc) {
    int c = cc * 32 + c0;
    float mean = st[(b * 32 + (c >> 4)) * 2];
    float rstd = st[(b * 32 + (c >> 4)) * 2 + 1];
    float sc = ns[c], bi = nbi[c];
    float4 v = *(const float4*)(x + (size_t)b * 524288 + (size_t)c * 1024 + t0 + tg);
    tile[(tg + 0) * 520 + c] = f2bf((v.x - mean) * rstd * sc + bi);
    tile[(tg + 1) * 520 + c] = f2bf((v.y - mean) * rstd * sc + bi);
    tile[(tg + 2) * 520 + c] = f2bf((v.z - mean) * rstd * sc + bi);
    tile[(tg + 3) * 520 + c] = f2bf((v.w - mean) * rstd * sc + bi);
  }
  __syncthreads();
#pragma unroll
  for (int i = 0; i < 8; ++i) {
    int chunk = i * 256 + tid;
    int tl2 = chunk >> 6;
    int c0b = (chunk & 63) * 8;
    uint4 d = *(const uint4*)(tile + tl2 * 520 + c0b);
    *(uint4*)(xnt + (size_t)b * 524288 + (size_t)(t0 + tl2) * 512 + c0b) = d;
  }
}

// ---------------- shared GEMM core: 128x128 tile, BK=64, K=512, single-buffer ----------------
// A: [M][512] bf16 row-major. B^T: [N][512] bf16 row-major. XOR-swizzled LDS.
static __device__ __forceinline__ void gemm_core(const u16* Abase, const u16* Bbase,
                                                 f32x4 acc[4][4], u16* As, u16* Bs,
                                                 int w, int l, int wm, int wn) {
  const int r8 = l >> 3, ch = l & 7;
  const int fr = l & 15, fq = l >> 4;
#pragma unroll 1
  for (int kt = 0; kt < 8; ++kt) {
    __syncthreads();
#pragma unroll
    for (int i = 0; i < 4; ++i) {
      int gi = (w << 2) + i;
      int row = (gi << 3) + r8;
      int xoff = ((ch ^ (row & 7)) << 4);
      gload_lds16((const char*)Abase + (size_t)row * 1024 + (kt << 7) + xoff,
                  (char*)As + (gi << 10));
      gload_lds16((const char*)Bbase + (size_t)row * 1024 + (kt << 7) + xoff,
                  (char*)Bs + (gi << 10));
    }
    __syncthreads();
#pragma unroll
    for (int kf = 0; kf < 2; ++kf) {
      bf16x8 af[4], bfv[4];
#pragma unroll
      for (int i = 0; i < 4; ++i) {
        int rowA = wm * 64 + i * 16 + fr;
        af[i] = *(const bf16x8*)(As + rowA * 64 + ((((kf << 2) + fq) ^ (rowA & 7)) << 3));
        int rowB = wn * 64 + i * 16 + fr;
        bfv[i] = *(const bf16x8*)(Bs + rowB * 64 + ((((kf << 2) + fq) ^ (rowB & 7)) << 3));
      }
#pragma unroll
      for (int i = 0; i < 4; ++i)
#pragma unroll
        for (int j = 0; j < 4; ++j)
          acc[i][j] = __builtin_amdgcn_mfma_f32_16x16x32_bf16(af[i], bfv[j], acc[i][j], 0, 0, 0);
    }
  }
}

// ---------------- QKV GEMM with LDS-transposed coalesced epilogue ----------------
__global__ __launch_bounds__(256) void gemm_qkv(const u16* __restrict__ Wq,
                                                const u16* __restrict__ Xnt,
                                                const float* __restrict__ bq,
                                                u16* __restrict__ qT,
                                                u16* __restrict__ kT,
                                                u16* __restrict__ vv) {
  __shared__ u16 SMEM[18432];  // gemm As=SMEM, Bs=SMEM+8192; epilogue SUB[wm]=SMEM+wm*9216
  int bid0 = blockIdx.x;
  int bid = (bid0 & 7) * 96 + (bid0 >> 3);  // bijective: 768 = 8*96
  int mb = bid % 12, nb = (bid / 12) % 8, b = bid / 96;
  int tid = threadIdx.x, w = tid >> 6, l = tid & 63;
  int wm = tid >> 7, wn = (tid >> 6) & 1;
  int fr = l & 15, fq = l >> 4;
  f32x4 acc[4][4];
#pragma unroll
  for (int i = 0; i < 4; ++i)
#pragma unroll
    for (int j = 0; j < 4; ++j) acc[i][j] = (f32x4){0.f, 0.f, 0.f, 0.f};

  gemm_core(Wq + (size_t)mb * 65536, Xnt + (size_t)b * 524288 + (size_t)nb * 65536,
            acc, SMEM, SMEM + 8192, w, l, wm, wn);

  __syncthreads();  // all gemm LDS reads done before epilogue overwrite

  int seg2 = mb * 2 + wm;       // 0..23: which 64-row o-segment
  int h = seg2 / 3, typ = seg2 % 3;  // 0=q 1=k 2=v
  size_t hb = (size_t)(b * 8 + h) * 65536;
  u16* SUB = SMEM + wm * 9216;

  if (typ < 2) {
    // q/k: SUB layout [t 128][72 pad], rows 144B (16B-aligned)
    float qksc = (typ == 0) ? 0.51011687f : 0.35355339f;  // q: 64^-.25*log2e ; k: 64^-.25
#pragma unroll
    for (int i = 0; i < 4; ++i) {
      int oi = i * 16 + fq * 4;
      float4 bb = *(const float4*)(bq + mb * 128 + wm * 64 + oi);
#pragma unroll
      for (int j = 0; j < 4; ++j) {
        int tl = wn * 64 + j * 16 + fr;
        f32x4 v = acc[i][j];
        uint2 pk;
        pk.x = (u32)f2bf((v[0] + bb.x) * qksc) | ((u32)f2bf((v[1] + bb.y) * qksc) << 16);
        pk.y = (u32)f2bf((v[2] + bb.z) * qksc) | ((u32)f2bf((v[3] + bb.w) * qksc) << 16);
        *(uint2*)(SUB + tl * 72 + oi) = pk;
      }
    }
  } else {
    // v: SUB layout [o 64][136 pad], rows 272B (16B-aligned)
#pragma unroll
    for (int i = 0; i < 4; ++i) {
      int oi = i * 16 + fq * 4;
      float4 bb = *(const float4*)(bq + mb * 128 + wm * 64 + oi);
      float bbv[4] = {bb.x, bb.y, bb.z, bb.w};
#pragma unroll
      for (int j = 0; j < 4; ++j) {
        int tl = wn * 64 + j * 16 + fr;
        f32x4 v = acc[i][j];
#pragma unroll
        for (int r = 0; r < 4; ++r)
          SUB[(oi + r) * 136 + tl] = f2bf(v[r] + bbv[r]);
      }
    }
  }
  __syncthreads();

  // coalesced store: each 128-thread half stores its own sub-tile
  int lt = tid & 127;
  if (typ < 2) {
    u16* dstb = (typ == 0 ? qT : kT) + hb;
#pragma unroll
    for (int it = 0; it < 8; ++it) {
      int slot = it * 128 + lt;
      int t = slot >> 3, chk = slot & 7;
      uint4 val = *(const uint4*)(SUB + t * 72 + chk * 8);
      *(uint4*)(dstb + (size_t)(nb * 128 + t) * 64 + chk * 8) = val;
    }
  } else {
#pragma unroll
    for (int it = 0; it < 8; ++it) {
      int slot = it * 128 + lt;
      int c = slot >> 4, chk = slot & 15;
      uint4 val = *(const uint4*)(SUB + c * 136 + chk * 8);
      *(uint4*)(vv + hb + (size_t)c * 1024 + nb * 128 + chk * 8) = val;
    }
  }
}

// ---------------- flash attention: staged LDS K/V, KVBLK=128, 8-wave blocks ----------------
__global__ __launch_bounds__(512) void attn(const u16* __restrict__ qT,
                                            const u16* __restrict__ kT,
                                            const u16* __restrict__ vv,
                                            u16* __restrict__ aT) {
  __shared__ u16 Ks[128 * 64];      // [s 128][c 64] swizzled, 16KB
  __shared__ u16 Vs[64 * 128];      // [c 64][s 128] swizzled (XOR within 128B half), 16KB
  __shared__ u16 Ps[8 * 16 * 72];   // per-wave P tile [16 t][64 s], row pad->72 (144B)
  int bid = blockIdx.x;
  // XCD swizzle: XCD x owns heads 8x..8x+7 -> 2MB K/V resident per XCD L2
  int bh = (bid & 7) * 8 + (bid >> 6);
  int tq = (bid >> 3) & 7;
  int tid = threadIdx.x, w = tid >> 6, l = tid & 63;
  int fr = l & 15, fq = l >> 4;
  int r8 = l >> 3, ch = l & 7;
  size_t hb = (size_t)bh * 65536;

  bf16x8 aq[2];  // Q frags, loop-invariant (q pre-scaled by 64^-0.25*log2e)
  {
    const u16* qp = qT + hb + (size_t)(tq * 128 + w * 16 + fr) * 64 + fq * 8;
    aq[0] = *(const bf16x8*)(qp);
    aq[1] = *(const bf16x8*)(qp + 32);
  }

  union { u32 u[4]; bf16x8 v; } onesu;
#pragma unroll
  for (int i = 0; i < 4; ++i) onesu.u[i] = 0x3F803F80u;
  const bf16x8 vone = onesu.v;  // all-ones B frag: every output col = row-sum

  f32x4 acc_o[4];
  f32x4 acc_s = (f32x4){0.f, 0.f, 0.f, 0.f};
#pragma unroll
  for (int nb = 0; nb < 4; ++nb) acc_o[nb] = (f32x4){0.f, 0.f, 0.f, 0.f};

  u16* pw = Ps + w * (16 * 72);

#pragma unroll 1
  for (int st = 0; st < 8; ++st) {
    __syncthreads();
#pragma unroll
    for (int j = 0; j < 2; ++j) {
      int gi = w * 2 + j;                 // 0..15
      // K: 8 s-rows (128B each) per load
      int row = gi * 8 + r8;              // s-local 0..127
      int xoff = ((ch ^ (row & 7)) << 4);
      gload_lds16((const char*)(kT + hb) + (size_t)(st * 128 + row) * 128 + xoff,
                  (char*)Ks + (gi << 10));
      // V: 4 c-rows (256B each) per load; XOR-swizzle within each 128B half
      int c = gi * 4 + (l >> 4);          // 0..63
      int half = (l >> 3) & 1;
      int ch8 = l & 7;
      int sxoff = half * 128 + ((ch8 ^ (c & 7)) << 4);
      gload_lds16((const char*)(vv + hb) + (size_t)c * 2048 + st * 256 + sxoff,
                  (char*)Vs + (gi << 10));
    }
    __syncthreads();

#pragma unroll
    for (int sh = 0; sh < 2; ++sh) {
      // S' = log2e*(q.k)/8 : D[t][s], 16x64 per wave per half
      f32x4 sa[4];
#pragma unroll
      for (int nb = 0; nb < 4; ++nb) sa[nb] = (f32x4){0.f, 0.f, 0.f, 0.f};
      __builtin_amdgcn_s_setprio(1);
#pragma unroll
      for (int nb = 0; nb < 4; ++nb) {
        int krow = sh * 64 + nb * 16 + fr;
#pragma unroll
        for (int kf = 0; kf < 2; ++kf) {
          bf16x8 bk = *(const bf16x8*)(Ks + krow * 64 + ((((kf << 2) + fq) ^ (krow & 7)) << 3));
          sa[nb] = __builtin_amdgcn_mfma_f32_16x16x32_bf16(aq[kf], bk, sa[nb], 0, 0, 0);
        }
      }
      __builtin_amdgcn_s_setprio(0);

      // P = 2^S' (no max subtraction); truncating bf16 cvt (bias cancels via acc_s)
#pragma unroll
      for (int nb = 0; nb < 4; ++nb)
#pragma unroll
        for (int r = 0; r < 4; ++r)
          pw[(fq * 4 + r) * 72 + nb * 16 + fr] = f2bf_t(exp2f(sa[nb][r]));

      bf16x8 ap[2];  // wave-private LDS round-trip
#pragma unroll
      for (int kf = 0; kf < 2; ++kf)
        ap[kf] = *(const bf16x8*)(pw + fr * 72 + kf * 32 + fq * 8);

      __builtin_amdgcn_s_setprio(1);
#pragma unroll
      for (int nb = 0; nb < 4; ++nb) {
        int vrow = nb * 16 + fr;
#pragma unroll
        for (int kf = 0; kf < 2; ++kf) {
          bf16x8 bv = *(const bf16x8*)(Vs + vrow * 128 + sh * 64 +
                                       ((((kf << 2) + fq) ^ (vrow & 7)) << 3));
          acc_o[nb] = __builtin_amdgcn_mfma_f32_16x16x32_bf16(ap[kf], bv, acc_o[nb], 0, 0, 0);
        }
      }
#pragma unroll
      for (int kf = 0; kf < 2; ++kf)
        acc_s = __builtin_amdgcn_mfma_f32_16x16x32_bf16(ap[kf], vone, acc_s, 0, 0, 0);
      __builtin_amdgcn_s_setprio(0);
    }
  }

  int b = bh >> 3, h = bh & 7;
  f32x4 invl;  // acc_s rows align with acc_o rows -> no shuffle needed
#pragma unroll
  for (int r = 0; r < 4; ++r) invl[r] = 1.f / acc_s[r];
#pragma unroll
  for (int nb = 0; nb < 4; ++nb) {
    f32x4 ov = acc_o[nb] * invl;
#pragma unroll
    for (int r = 0; r < 4; ++r) {
      int t = tq * 128 + w * 16 + fq * 4 + r;
      aT[(size_t)b * 524288 + (size_t)t * 512 + h * 64 + nb * 16 + fr] = f2bf(ov[r]);
    }
  }
}

// ---------------- proj GEMM + residual ----------------
__global__ __launch_bounds__(256) void gemm_proj(const u16* __restrict__ Wp,
                                                 const u16* __restrict__ aT,
                                                 const float* __restrict__ bp,
                                                 const float* __restrict__ x,
                                                 float* __restrict__ out) {
  __shared__ u16 As[128 * 64];
  __shared__ u16 Bs[128 * 64];
  int bid0 = blockIdx.x;
  int bid = (bid0 & 7) * 32 + (bid0 >> 3);  // bijective: 256 = 8*32
  int mb = bid & 3, nb = (bid >> 2) & 7, b = bid >> 5;
  int tid = threadIdx.x, w = tid >> 6, l = tid & 63;
  int wm = w >> 1, wn = w & 1;
  f32x4 acc[4][4];
#pragma unroll
  for (int i = 0; i < 4; ++i)
#pragma unroll
    for (int j = 0; j < 4; ++j) acc[i][j] = (f32x4){0.f, 0.f, 0.f, 0.f};

  gemm_core(Wp + (size_t)mb * 65536, aT + (size_t)b * 524288 + (size_t)nb * 65536,
            acc, As, Bs, w, l, wm, wn);

  int fr = l & 15, fq = l >> 4;
#pragma unroll
  for (int i = 0; i < 4; ++i) {
    int o0 = mb * 128 + wm * 64 + i * 16 + fq * 4;
    float b0 = bp[o0], b1 = bp[o0 + 1], b2 = bp[o0 + 2], b3 = bp[o0 + 3];
#pragma unroll
    for (int j = 0; j < 4; ++j) {
      int t = nb * 128 + wn * 64 + j * 16 + fr;
      f32x4 v = acc[i][j];
      size_t base = (size_t)b * 524288 + (size_t)o0 * 1024 + t;
      out[base] = x[base] + v[0] + b0;
      out[base + 1024] = x[base + 1024] + v[1] + b1;
      out[base + 2048] = x[base + 2048] + v[2] + b2;
      out[base + 3072] = x[base + 3072] + v[3] + b3;
    }
  }
}

extern "C" void kernel_launch(void* const* d_in, const int* in_sizes, int n_in,
                              void* d_out, int out_size, void* d_ws, size_t ws_size,
                              hipStream_t stream) {
  const float* x = (const float*)d_in[0];
  const float* ns = (const float*)d_in[1];
  const float* nbi = (const float*)d_in[2];
  const float* wq = (const float*)d_in[3];
  const float* bq = (const float*)d_in[4];
  const float* wp = (const float*)d_in[5];
  const float* bp = (const float*)d_in[6];
  float* out = (float*)d_out;
  char* ws = (char*)d_ws;

  u16* wqb = (u16*)(ws);                          // 1,572,864 B
  u16* wpb = (u16*)(ws + 1572864);                //   524,288 B
  float* st = (float*)(ws + 2097152);             //     2,048 B
  u16* xnt = (u16*)(ws + 2101248);                // 8,388,608 B  [b][t][c] bf16
  u16* qT = (u16*)(ws + 2101248 + 8388608);       // 8,388,608 B  [bh][t][64] bf16 (pre-scaled)
  u16* kT = (u16*)(ws + 2101248 + 2 * 8388608);   // 8,388,608 B  [bh][s][64] bf16 (pre-scaled)
  u16* vv = (u16*)(ws + 2101248 + 3 * 8388608);   // 8,388,608 B  [bh][64][s] bf16
  u16* aT = xnt;  // reuse: xnt fully consumed by gemm_qkv before attn writes aT

  hipLaunchKernelGGL(prep, dim3(1280), dim3(256), 0, stream, wq, wp, x, wqb, wpb, st);
  hipLaunchKernelGGL(gn_apply, dim3(256), dim3(256), 0, stream, x, st, ns, nbi, xnt);
  hipLaunchKernelGGL(gemm_qkv, dim3(768), dim3(256), 0, stream, wqb, xnt, bq, qT, kT, vv);
  hipLaunchKernelGGL(attn, dim3(512), dim3(512), 0, stream, qT, kT, vv, aT);
  hipLaunchKernelGGL(gemm_proj, dim3(256), dim3(256), 0, stream, wpb, aT, bp, x, out);
}